// Round 7
// baseline (190.256 us; speedup 1.0000x reference)
//
#include <hip/hip_runtime.h>

// MeshTokenizer: B=64, NV=8192, NF=16384.
// Outputs concatenated flat as float32:
//   [0] input_ids        64 x 163841   @ 0
//   [1] attention_mask   64 x 163841   @ 10485824   (all ones)
//   [2] codes            64x16384x3x3  @ 20971648
//   [3] discrete_face_coords (==codes) @ 30408832
//   [4] recon_faces      64x1x3x3      @ 39846016
//
// R7 experiment: TEMPORAL stream separation. R6's single kernel drives 4
// concurrent write streams per CU and runs at ~2.3 TB/s effective (K~75us vs
// ~28us traffic floor). The harness's own 1-stream fill hits 6.7 TB/s.
// Sequential kernels, ~1 write stream each:
//   A: pack verts (per-vertex codes, 3x7b in a dword) -> d_ws (2 MB)
//   B: mask = pure vf4 fill (41.9 MB)  [exact: 10485824 = 4*2621456]
//   C: gather + input_ids (41.9 MB, LDS transpose, phase-aligned)
//   D: gather + codes x2 (75.4 MB)  [gather re-done; table L2-hot]

#define B_      64
#define NV_     8192
#define NF_     16384
#define ROW_    (NF_ * 10 + 1)   // 163841
#define OFF_IDS   ((size_t)0)
#define OFF_MASK  ((size_t)10485824)
#define OFF_C1    ((size_t)20971648)
#define OFF_C2    ((size_t)30408832)
#define OFF_REC   ((size_t)39846016)
#define NV4_MASK  2621456        // 10485824 / 4, exact

typedef float vf4 __attribute__((ext_vector_type(4)));

__device__ __forceinline__ float disc1(float x) {
    // (x-LO)/(HI-LO)*128 - 0.5 == (x+1)*64 - 0.5 bit-exactly; round-half-even
    float r = rintf((x + 1.0f) * 64.0f - 0.5f);
    return fminf(fmaxf(r, 0.0f), 127.0f);
}

// ---- A: per-vertex discretize + pack (64*8192 = 524288 verts) ----
__global__ __launch_bounds__(256) void pack_verts_kernel(
        const float* __restrict__ verts,
        unsigned int* __restrict__ packed) {
    const int g = blockIdx.x * 256 + threadIdx.x;
    const float* vp = verts + (size_t)g * 3;
    const unsigned int c0 = (unsigned int)disc1(vp[0]);
    const unsigned int c1 = (unsigned int)disc1(vp[1]);
    const unsigned int c2 = (unsigned int)disc1(vp[2]);
    packed[g] = c0 | (c1 << 8) | (c2 << 16);
}

// ---- B: attention_mask pure fill, single address stream ----
__global__ __launch_bounds__(256) void mask_fill_kernel(float* __restrict__ out) {
    const vf4 ones = {1.0f, 1.0f, 1.0f, 1.0f};
    vf4* m4 = (vf4*)(out + OFF_MASK);
    for (int i = blockIdx.x * 256 + threadIdx.x; i < NV4_MASK; i += 256 * 1024)
        m4[i] = ones;
}

// ---- C: gather + input_ids. One block = 256 consecutive faces of batch b.
// Thread t (face j) owns ids[j*10 .. j*10+9]; block span = 2560 floats at
// S = b*163841 + j0*10; phase p=S&3 baked into LDS for aligned dwordx4. ----
__global__ __launch_bounds__(256) void ids_kernel(
        const unsigned int* __restrict__ packed,
        const int*          __restrict__ faces,
        float*              __restrict__ out) {
    const int t   = threadIdx.x;
    const int b   = blockIdx.x >> 6;
    const int j0  = (blockIdx.x & 63) << 8;
    const int j   = j0 + t;

    __shared__ __align__(16) float s_ids[2564];

    const int* fp = faces + ((size_t)b * NF_ + j) * 3;
    const unsigned int* pb = packed + (size_t)b * NV_;
    const unsigned int pk0 = pb[fp[0]], pk1 = pb[fp[1]], pk2 = pb[fp[2]];

    const size_t S  = (size_t)b * ROW_ + (size_t)j0 * 10;
    const int    p  = (int)(S & 3);
    const int    pp = (4 - p) & 3;

    float* base = &s_ids[p + t * 10];
    base[0] = (j == 0) ? -1.0f : 128.0f;   // sep of face j-1 / lead pad
    base[1] = (float)(pk0 & 127u);
    base[2] = (float)((pk0 >> 8) & 127u);
    base[3] = (float)((pk0 >> 16) & 127u);
    base[4] = (float)(pk1 & 127u);
    base[5] = (float)((pk1 >> 8) & 127u);
    base[6] = (float)((pk1 >> 16) & 127u);
    base[7] = (float)(pk2 & 127u);
    base[8] = (float)((pk2 >> 8) & 127u);
    base[9] = (float)((pk2 >> 16) & 127u);
    __syncthreads();

    float* out_ids = out + OFF_IDS;
    const size_t A   = S + pp;
    const int    nf4 = (p == 0) ? 640 : 639;
    const int    lb  = (p == 0) ? 0 : 1;
    const vf4*   s4  = (const vf4*)s_ids;
    vf4* ids4 = (vf4*)(out_ids + A);
    for (int f4 = t; f4 < nf4; f4 += 256) ids4[f4] = s4[lb + f4];
    if (t < pp)              out_ids[S + t] = s_ids[p + t];
    if (t >= 4 && t < 4 + p) out_ids[S + 2560 - p + (t - 4)] = s_ids[2560 + (t - 4)];
    if (t == 0 && j0 == NF_ - 256)
        out_ids[(size_t)b * ROW_ + (ROW_ - 1)] = -1.0f;
}

// ---- D: gather + codes x2 (+ recon). Same block mapping as C. ----
__global__ __launch_bounds__(256) void codes_kernel(
        const unsigned int* __restrict__ packed,
        const int*          __restrict__ faces,
        float*              __restrict__ out) {
    const int t   = threadIdx.x;
    const int b   = blockIdx.x >> 6;
    const int j0  = (blockIdx.x & 63) << 8;
    const int j   = j0 + t;

    __shared__ __align__(16) float s_codes[2304];

    const int* fp = faces + ((size_t)b * NF_ + j) * 3;
    const unsigned int* pb = packed + (size_t)b * NV_;
    float code_f[9];
    #pragma unroll
    for (int vi = 0; vi < 3; ++vi) {
        const unsigned int pk = pb[fp[vi]];
        code_f[vi * 3 + 0] = (float)(pk & 127u);
        code_f[vi * 3 + 1] = (float)((pk >> 8) & 127u);
        code_f[vi * 3 + 2] = (float)((pk >> 16) & 127u);
    }
    #pragma unroll
    for (int k = 0; k < 9; ++k) s_codes[t * 9 + k] = code_f[k];
    __syncthreads();

    const size_t baseC = ((size_t)b * NF_ + j0) * 9;
    const vf4* sc4 = (const vf4*)s_codes;
    vf4* c1p = (vf4*)(out + OFF_C1 + baseC);
    vf4* c2p = (vf4*)(out + OFF_C2 + baseC);
    for (int f4 = t; f4 < 576; f4 += 256) {
        vf4 v = sc4[f4];
        c1p[f4] = v;
        c2p[f4] = v;
    }

    if (t == 0 && j0 == 0) {   // face 0 -> recon_faces
        float* out_rec = out + OFF_REC;
        #pragma unroll
        for (int k = 0; k < 9; ++k)
            out_rec[b * 9 + k] = (code_f[k] + 0.5f) * 0.015625f - 1.0f;
    }
}

extern "C" void kernel_launch(void* const* d_in, const int* in_sizes, int n_in,
                              void* d_out, int out_size, void* d_ws, size_t ws_size,
                              hipStream_t stream) {
    const float*  verts  = (const float*)d_in[0];
    const int*    faces  = (const int*)d_in[1];
    float*        out    = (float*)d_out;
    unsigned int* packed = (unsigned int*)d_ws;   // 2 MB

    pack_verts_kernel<<<dim3(B_ * NV_ / 256), dim3(256), 0, stream>>>(verts, packed);
    mask_fill_kernel <<<dim3(1024),            dim3(256), 0, stream>>>(out);
    ids_kernel       <<<dim3(B_ * (NF_ / 256)), dim3(256), 0, stream>>>(packed, faces, out);
    codes_kernel     <<<dim3(B_ * (NF_ / 256)), dim3(256), 0, stream>>>(packed, faces, out);
}

// Round 8
// 183.537 us; speedup vs baseline: 1.0366x; 1.0366x over previous
//
#include <hip/hip_runtime.h>

// MeshTokenizer: B=64, NV=8192, NF=16384.
// Outputs concatenated flat as float32:
//   [0] input_ids        64 x 163841   @ 0
//   [1] attention_mask   64 x 163841   @ 10485824   (all ones)
//   [2] codes            64x16384x3x3  @ 20971648
//   [3] discrete_face_coords (==codes) @ 30408832
//   [4] recon_faces      64x1x3x3      @ 39846016
// ~174 MB HBM traffic -> ~28 us floor @6.3 TB/s.
//
// R8 = R6 (best, 179.7us) + two micro-fixes:
//  - faces loaded coalesced per-wave into LDS, redistributed wave-locally
//    (3x fewer L1 line-requests on the 12.6 MB faces stream)
//  - compile-time store trip counts: always 639 vf4 for ids/mask from the
//    phase-aligned start + pp head / (4-pp) tail scalars -> unrolled stores
// History: R4 packed gather -4.8; R5 spatial split +24; R6 no-nt+hoist -5.9;
// R7 temporal split +10.6.

#define B_      64
#define NV_     8192
#define NF_     16384
#define ROW_    (NF_ * 10 + 1)   // 163841 (odd stride -> per-batch dword phase b&3)
#define OFF_IDS   ((size_t)0)
#define OFF_MASK  ((size_t)10485824)
#define OFF_C1    ((size_t)20971648)
#define OFF_C2    ((size_t)30408832)
#define OFF_REC   ((size_t)39846016)

typedef float vf4 __attribute__((ext_vector_type(4)));

__device__ __forceinline__ float disc1(float x) {
    // (x-LO)/(HI-LO)*128 - 0.5 == (x+1)*64 - 0.5 bit-exactly; round-half-even
    float r = rintf((x + 1.0f) * 64.0f - 0.5f);
    return fminf(fmaxf(r, 0.0f), 127.0f);
}

// ---- Pass A: per-vertex discretize + pack (64*8192 = 524288 verts) ----
__global__ __launch_bounds__(256) void pack_verts_kernel(
        const float* __restrict__ verts,
        unsigned int* __restrict__ packed) {
    const int g = blockIdx.x * 256 + threadIdx.x;
    const float* vp = verts + (size_t)g * 3;
    const unsigned int c0 = (unsigned int)disc1(vp[0]);
    const unsigned int c1 = (unsigned int)disc1(vp[1]);
    const unsigned int c2 = (unsigned int)disc1(vp[2]);
    packed[g] = c0 | (c1 << 8) | (c2 << 16);
}

// ---- Pass B: one block = 256 consecutive faces of one batch. Thread t
// (face j) owns input_ids [j*10, j*10+9]; block span = contiguous 2560 floats
// at S = b*163841 + j0*10. Phase p = S&3 baked into LDS so global stores are
// 16B-aligned dwordx4; pp head + (4-pp) tail elems scalar.
__global__ __launch_bounds__(256) void mesh_tok_kernel(
        const unsigned int* __restrict__ packed,
        const int*          __restrict__ faces,
        float*              __restrict__ out) {
    const int t   = threadIdx.x;
    const int blk = blockIdx.x;
    const int b   = blk >> 6;            // batch
    const int j0  = (blk & 63) << 8;     // first face of this block
    const int j   = j0 + t;

    __shared__ __align__(16) float s_ids[2564];
    __shared__ __align__(16) float s_codes[2304];
    __shared__ int s_faces[768];

    const size_t S  = (size_t)b * ROW_ + (size_t)j0 * 10;
    const int    p  = (int)(S & 3);                        // == b & 3
    const int    pp = (4 - p) & 3;
    const size_t A  = S + pp;                              // 16B-aligned start

    float* out_ids  = out + OFF_IDS;
    float* out_mask = out + OFF_MASK;

    // ---- faces: coalesced per-wave load -> LDS, wave-local redistribute ----
    // wave w owns faces [w*64, w*64+64) whose 192 dwords are tile [w*192,(w+1)*192).
    {
        const int w    = t >> 6;            // wave id
        const int l    = t & 63;            // lane
        const int tb   = w * 192;           // tile base in s_faces
        const int* fsrc = faces + ((size_t)b * NF_ + j0) * 3 + tb;
        s_faces[tb + l]       = fsrc[l];
        s_faces[tb + l + 64]  = fsrc[l + 64];
        s_faces[tb + l + 128] = fsrc[l + 128];
        // same-wave producer/consumer: lgkmcnt ordering suffices, no barrier
    }
    const unsigned int* pb = packed + (size_t)b * NV_;
    const unsigned int pk0 = pb[s_faces[t * 3 + 0]];
    const unsigned int pk1 = pb[s_faces[t * 3 + 1]];
    const unsigned int pk2 = pb[s_faces[t * 3 + 2]];

    // ---- mask: input-independent, store while gathers are in flight ----
    {
        const vf4 ones = {1.0f, 1.0f, 1.0f, 1.0f};
        vf4* mask4 = (vf4*)(out_mask + A);
        mask4[t]       = ones;
        mask4[t + 256] = ones;
        if (t < 127) mask4[t + 512] = ones;                // 639 total
        if (t < pp)  out_mask[S + t] = 1.0f;               // head
        if (t >= 8 && t < 8 + (4 - pp))                    // tail
            out_mask[S + pp + 2556 + (t - 8)] = 1.0f;
        if (t == 0 && j0 == NF_ - 256)
            out_mask[(size_t)b * ROW_ + (ROW_ - 1)] = 1.0f;
    }

    // ---- unpack codes ----
    float code_f[9];
    const unsigned int pk[3] = {pk0, pk1, pk2};
    #pragma unroll
    for (int vi = 0; vi < 3; ++vi) {
        code_f[vi * 3 + 0] = (float)(pk[vi] & 127u);
        code_f[vi * 3 + 1] = (float)((pk[vi] >> 8) & 127u);
        code_f[vi * 3 + 2] = (float)((pk[vi] >> 16) & 127u);
    }

    // ---- stage ids (phase-shifted) + codes ----
    s_ids[p + t * 10] = (j == 0) ? -1.0f : 128.0f;         // sep of j-1 / lead pad
    #pragma unroll
    for (int k = 0; k < 9; ++k) {
        s_ids[p + t * 10 + 1 + k] = code_f[k];
        s_codes[t * 9 + k]        = code_f[k];
    }
    __syncthreads();

    // ---- ids: aligned vf4 stores (LDS vf4 index = f4 + (p?1:0)) ----
    {
        const int  lb  = (p == 0) ? 0 : 1;
        const vf4* s4  = (const vf4*)s_ids;
        vf4* ids4 = (vf4*)(out_ids + A);
        ids4[t]       = s4[lb + t];
        ids4[t + 256] = s4[lb + t + 256];
        if (t < 127) ids4[t + 512] = s4[lb + t + 512];     // 639 total
        if (t < pp)  out_ids[S + t] = s_ids[p + t];        // head
        if (t >= 8 && t < 8 + (4 - pp))                    // tail
            out_ids[S + pp + 2556 + (t - 8)] = s_ids[p + pp + 2556 + (t - 8)];
    }

    // ---- codes x2: naturally 16B-aligned, 576 vf4 each ----
    const size_t baseC = ((size_t)b * NF_ + j0) * 9;
    const vf4* sc4 = (const vf4*)s_codes;
    vf4* c1p = (vf4*)(out + OFF_C1 + baseC);
    vf4* c2p = (vf4*)(out + OFF_C2 + baseC);
    {
        vf4 v0 = sc4[t], v1 = sc4[t + 256];
        c1p[t]       = v0;
        c2p[t]       = v0;
        c1p[t + 256] = v1;
        c2p[t + 256] = v1;
        if (t < 64) {
            vf4 v2 = sc4[t + 512];
            c1p[t + 512] = v2;
            c2p[t + 512] = v2;
        }
    }

    // ---- final ids pad + recon_faces ----
    if (t == 0) {
        if (j0 == NF_ - 256)
            out_ids[(size_t)b * ROW_ + (ROW_ - 1)] = -1.0f;
        if (j0 == 0) {  // thread 0 of first block holds face 0's codes
            float* out_rec = out + OFF_REC;
            #pragma unroll
            for (int k = 0; k < 9; ++k)
                out_rec[b * 9 + k] = (code_f[k] + 0.5f) * 0.015625f - 1.0f;
        }
    }
}

extern "C" void kernel_launch(void* const* d_in, const int* in_sizes, int n_in,
                              void* d_out, int out_size, void* d_ws, size_t ws_size,
                              hipStream_t stream) {
    const float*  verts  = (const float*)d_in[0];
    const int*    faces  = (const int*)d_in[1];
    float*        out    = (float*)d_out;
    unsigned int* packed = (unsigned int*)d_ws;   // 2 MB: 64*8192 uints

    pack_verts_kernel<<<dim3(B_ * NV_ / 256), dim3(256), 0, stream>>>(verts, packed);
    mesh_tok_kernel  <<<dim3(B_ * (NF_ / 256)), dim3(256), 0, stream>>>(packed, faces, out);
}

// Round 9
// 181.104 us; speedup vs baseline: 1.0505x; 1.0134x over previous
//
#include <hip/hip_runtime.h>

// MeshTokenizer: B=64, NV=8192, NF=16384.
// Outputs concatenated flat as float32:
//   [0] input_ids        64 x 163841   @ 0
//   [1] attention_mask   64 x 163841   @ 10485824   (all ones)
//   [2] codes            64x16384x3x3  @ 20971648
//   [3] discrete_face_coords (==codes) @ 30408832
//   [4] recon_faces      64x1x3x3      @ 39846016
// ~178 MB HBM traffic -> ~28 us floor @6.3 TB/s.
//
// R9 = R6 (best, 179.7us) + compile-time store trip counts ONLY.
// (R8 bundled this with a faces->LDS redistribute and regressed +3.8;
//  the LDS round trip serialized lgkmcnt ahead of the gather chain — reverted.)
// History: R4 packed gather -4.8; R5 spatial split +24; R6 no-nt+hoist -5.9;
// R7 temporal split +10.6; R8 faces-LDS+unroll +3.8.

#define B_      64
#define NV_     8192
#define NF_     16384
#define ROW_    (NF_ * 10 + 1)   // 163841 (odd stride -> per-batch dword phase b&3)
#define OFF_IDS   ((size_t)0)
#define OFF_MASK  ((size_t)10485824)
#define OFF_C1    ((size_t)20971648)
#define OFF_C2    ((size_t)30408832)
#define OFF_REC   ((size_t)39846016)

typedef float vf4 __attribute__((ext_vector_type(4)));

__device__ __forceinline__ float disc1(float x) {
    // (x-LO)/(HI-LO)*128 - 0.5 == (x+1)*64 - 0.5 bit-exactly; round-half-even
    float r = rintf((x + 1.0f) * 64.0f - 0.5f);
    return fminf(fmaxf(r, 0.0f), 127.0f);
}

// ---- Pass A: per-vertex discretize + pack (64*8192 = 524288 verts) ----
__global__ __launch_bounds__(256) void pack_verts_kernel(
        const float* __restrict__ verts,
        unsigned int* __restrict__ packed) {
    const int g = blockIdx.x * 256 + threadIdx.x;
    const float* vp = verts + (size_t)g * 3;
    const unsigned int c0 = (unsigned int)disc1(vp[0]);
    const unsigned int c1 = (unsigned int)disc1(vp[1]);
    const unsigned int c2 = (unsigned int)disc1(vp[2]);
    packed[g] = c0 | (c1 << 8) | (c2 << 16);
}

// ---- Pass B: one block = 256 consecutive faces of one batch. Thread t
// (face j) owns input_ids [j*10, j*10+9]; block span = contiguous 2560 floats
// at S = b*163841 + j0*10. Phase p = S&3 baked into LDS so global stores are
// 16B-aligned dwordx4; pp head + p tail elems scalar. Store loops are
// compile-time: 639 vf4 always (covers [A, A+2556)), head pp, tail 4-pp.
__global__ __launch_bounds__(256) void mesh_tok_kernel(
        const unsigned int* __restrict__ packed,
        const int*          __restrict__ faces,
        float*              __restrict__ out) {
    const int t   = threadIdx.x;
    const int blk = blockIdx.x;
    const int b   = blk >> 6;            // batch
    const int j0  = (blk & 63) << 8;     // first face of this block
    const int j   = j0 + t;

    __shared__ __align__(16) float s_ids[2564];
    __shared__ __align__(16) float s_codes[2304];

    const size_t S  = (size_t)b * ROW_ + (size_t)j0 * 10;
    const int    p  = (int)(S & 3);                        // == b & 3
    const int    pp = (4 - p) & 3;
    const size_t A  = S + pp;                              // 16B-aligned start

    float* out_ids  = out + OFF_IDS;
    float* out_mask = out + OFF_MASK;

    // ---- issue gather loads (direct per-lane; L1 merges stride-12 lines) ----
    const int* fp = faces + ((size_t)b * NF_ + j) * 3;
    const unsigned int* pb = packed + (size_t)b * NV_;
    const int i0 = fp[0], i1 = fp[1], i2 = fp[2];
    const unsigned int pk0 = pb[i0], pk1 = pb[i1], pk2 = pb[i2];

    // ---- mask: input-independent, store while gathers are in flight ----
    {
        const vf4 ones = {1.0f, 1.0f, 1.0f, 1.0f};
        vf4* mask4 = (vf4*)(out_mask + A);
        mask4[t]       = ones;
        mask4[t + 256] = ones;
        if (t < 127) mask4[t + 512] = ones;                // 639 total
        if (t < pp)  out_mask[S + t] = 1.0f;               // head
        if (t >= 8 && t < 8 + (4 - pp))                    // tail
            out_mask[S + pp + 2556 + (t - 8)] = 1.0f;
        if (t == 0 && j0 == NF_ - 256)
            out_mask[(size_t)b * ROW_ + (ROW_ - 1)] = 1.0f;
    }

    // ---- unpack codes ----
    float code_f[9];
    const unsigned int pk[3] = {pk0, pk1, pk2};
    #pragma unroll
    for (int vi = 0; vi < 3; ++vi) {
        code_f[vi * 3 + 0] = (float)(pk[vi] & 127u);
        code_f[vi * 3 + 1] = (float)((pk[vi] >> 8) & 127u);
        code_f[vi * 3 + 2] = (float)((pk[vi] >> 16) & 127u);
    }

    // ---- stage ids (phase-shifted) + codes ----
    s_ids[p + t * 10] = (j == 0) ? -1.0f : 128.0f;         // sep of j-1 / lead pad
    #pragma unroll
    for (int k = 0; k < 9; ++k) {
        s_ids[p + t * 10 + 1 + k] = code_f[k];
        s_codes[t * 9 + k]        = code_f[k];
    }
    __syncthreads();

    // ---- ids: aligned vf4 stores (LDS vf4 index shifted by lb) ----
    {
        const int  lb  = (p == 0) ? 0 : 1;
        const vf4* s4  = (const vf4*)s_ids;
        vf4* ids4 = (vf4*)(out_ids + A);
        ids4[t]       = s4[lb + t];
        ids4[t + 256] = s4[lb + t + 256];
        if (t < 127) ids4[t + 512] = s4[lb + t + 512];     // 639 total
        if (t < pp)  out_ids[S + t] = s_ids[p + t];        // head
        if (t >= 8 && t < 8 + (4 - pp))                    // tail
            out_ids[S + pp + 2556 + (t - 8)] = s_ids[p + pp + 2556 + (t - 8)];
    }

    // ---- codes x2: naturally 16B-aligned, 576 vf4 each ----
    const size_t baseC = ((size_t)b * NF_ + j0) * 9;
    const vf4* sc4 = (const vf4*)s_codes;
    vf4* c1p = (vf4*)(out + OFF_C1 + baseC);
    vf4* c2p = (vf4*)(out + OFF_C2 + baseC);
    {
        vf4 v0 = sc4[t], v1 = sc4[t + 256];
        c1p[t]       = v0;
        c2p[t]       = v0;
        c1p[t + 256] = v1;
        c2p[t + 256] = v1;
        if (t < 64) {
            vf4 v2 = sc4[t + 512];
            c1p[t + 512] = v2;
            c2p[t + 512] = v2;
        }
    }

    // ---- final ids pad + recon_faces ----
    if (t == 0) {
        if (j0 == NF_ - 256)
            out_ids[(size_t)b * ROW_ + (ROW_ - 1)] = -1.0f;
        if (j0 == 0) {  // thread 0 of first block holds face 0's codes
            float* out_rec = out + OFF_REC;
            #pragma unroll
            for (int k = 0; k < 9; ++k)
                out_rec[b * 9 + k] = (code_f[k] + 0.5f) * 0.015625f - 1.0f;
        }
    }
}

extern "C" void kernel_launch(void* const* d_in, const int* in_sizes, int n_in,
                              void* d_out, int out_size, void* d_ws, size_t ws_size,
                              hipStream_t stream) {
    const float*  verts  = (const float*)d_in[0];
    const int*    faces  = (const int*)d_in[1];
    float*        out    = (float*)d_out;
    unsigned int* packed = (unsigned int*)d_ws;   // 2 MB: 64*8192 uints

    pack_verts_kernel<<<dim3(B_ * NV_ / 256), dim3(256), 0, stream>>>(verts, packed);
    mesh_tok_kernel  <<<dim3(B_ * (NF_ / 256)), dim3(256), 0, stream>>>(packed, faces, out);
}

// Round 11
// 180.230 us; speedup vs baseline: 1.0556x; 1.0048x over previous
//
#include <hip/hip_runtime.h>

// MeshTokenizer: B=64, NV=8192, NF=16384.
// Outputs concatenated flat as float32:
//   [0] input_ids        64 x 163841   @ 0
//   [1] attention_mask   64 x 163841   @ 10485824   (all ones)
//   [2] codes            64x16384x3x3  @ 20971648
//   [3] discrete_face_coords (==codes) @ 30408832
//   [4] recon_faces      64x1x3x3      @ 39846016
// ~178 MB HBM traffic -> ~29 us kernel floor @6.3 TB/s.
//
// FINAL = R6 verbatim (best measured: 179.7 us end-to-end incl. ~135 us
// harness poison/restore). R10's run of this exact source died in a pytest
// core dump (infra flake, no kernel/compile/numeric error) — resubmitted.
// Axes measured in isolation:
//   R3 vf4+nt stores: 0 | R4 packed vertex-code table (L1-resident): -4.8
//   R5 spatial stream split: +24 | R6 drop-nt + hoist mask stores: -5.9
//   R7 temporal stream split: +10.6 | R8 faces->LDS redistribute: ~+2.4
//   R9 compile-time store trip counts: +1.4

#define B_      64
#define NV_     8192
#define NF_     16384
#define ROW_    (NF_ * 10 + 1)   // 163841 (odd stride -> per-batch dword phase b&3)
#define OFF_IDS   ((size_t)0)
#define OFF_MASK  ((size_t)10485824)
#define OFF_C1    ((size_t)20971648)
#define OFF_C2    ((size_t)30408832)
#define OFF_REC   ((size_t)39846016)

typedef float vf4 __attribute__((ext_vector_type(4)));

__device__ __forceinline__ float disc1(float x) {
    // (x-LO)/(HI-LO)*128 - 0.5 == (x+1)*64 - 0.5 bit-exactly; round-half-even
    float r = rintf((x + 1.0f) * 64.0f - 0.5f);
    return fminf(fmaxf(r, 0.0f), 127.0f);
}

// ---- Pass A: per-vertex discretize + pack (64*8192 = 524288 verts) ----
__global__ __launch_bounds__(256) void pack_verts_kernel(
        const float* __restrict__ verts,
        unsigned int* __restrict__ packed) {
    const int g = blockIdx.x * 256 + threadIdx.x;
    const float* vp = verts + (size_t)g * 3;
    const unsigned int c0 = (unsigned int)disc1(vp[0]);
    const unsigned int c1 = (unsigned int)disc1(vp[1]);
    const unsigned int c2 = (unsigned int)disc1(vp[2]);
    packed[g] = c0 | (c1 << 8) | (c2 << 16);
}

// ---- Pass B: one block = 256 consecutive faces of one batch. Thread t
// (face j) owns input_ids [j*10, j*10+9]; block span = contiguous 2560 floats
// at S = b*163841 + j0*10. Phase p = S&3 baked into LDS so global stores are
// 16B-aligned dwordx4; <=3 head + <=3 tail elems scalar.
__global__ __launch_bounds__(256) void mesh_tok_kernel(
        const unsigned int* __restrict__ packed,
        const int*          __restrict__ faces,
        float*              __restrict__ out) {
    const int t   = threadIdx.x;
    const int blk = blockIdx.x;
    const int b   = blk >> 6;            // batch
    const int j0  = (blk & 63) << 8;     // first face of this block
    const int j   = j0 + t;

    __shared__ __align__(16) float s_ids[2564];
    __shared__ __align__(16) float s_codes[2304];

    const size_t S  = (size_t)b * ROW_ + (size_t)j0 * 10;
    const int    p  = (int)(S & 3);                        // == b & 3
    const int    pp = (4 - p) & 3;
    const size_t A  = S + pp;                              // 16B-aligned start
    const int    nf4 = (p == 0) ? 640 : 639;
    const int    lb  = (p == 0) ? 0 : 1;

    float* out_ids  = out + OFF_IDS;
    float* out_mask = out + OFF_MASK;

    // ---- issue gather loads (face idx -> packed codes) ----
    const int* fp = faces + ((size_t)b * NF_ + j) * 3;
    const unsigned int* pb = packed + (size_t)b * NV_;
    const int i0 = fp[0], i1 = fp[1], i2 = fp[2];
    const unsigned int pk0 = pb[i0], pk1 = pb[i1], pk2 = pb[i2];

    // ---- mask: input-independent, store while gathers are in flight ----
    {
        const vf4 ones = {1.0f, 1.0f, 1.0f, 1.0f};
        vf4* mask4 = (vf4*)(out_mask + A);
        for (int f4 = t; f4 < nf4; f4 += 256) mask4[f4] = ones;
        if (t < pp)              out_mask[S + t] = 1.0f;
        if (t >= 4 && t < 4 + p) out_mask[S + 2560 - p + (t - 4)] = 1.0f;
        if (t == 0) {
            if (j0 == NF_ - 256) out_mask[(size_t)b * ROW_ + (ROW_ - 1)] = 1.0f;
        }
    }

    // ---- unpack codes ----
    float code_f[9];
    const unsigned int pk[3] = {pk0, pk1, pk2};
    #pragma unroll
    for (int vi = 0; vi < 3; ++vi) {
        code_f[vi * 3 + 0] = (float)(pk[vi] & 127u);
        code_f[vi * 3 + 1] = (float)((pk[vi] >> 8) & 127u);
        code_f[vi * 3 + 2] = (float)((pk[vi] >> 16) & 127u);
    }

    // ---- stage ids (phase-shifted) + codes ----
    s_ids[p + t * 10] = (j == 0) ? -1.0f : 128.0f;         // sep of j-1 / lead pad
    #pragma unroll
    for (int k = 0; k < 9; ++k) {
        s_ids[p + t * 10 + 1 + k] = code_f[k];
        s_codes[t * 9 + k]        = code_f[k];
    }
    __syncthreads();

    // ---- ids: aligned vf4 stores ----
    {
        const vf4* s4 = (const vf4*)s_ids;
        vf4* ids4 = (vf4*)(out_ids + A);
        for (int f4 = t; f4 < nf4; f4 += 256) ids4[f4] = s4[lb + f4];
        if (t < pp)              out_ids[S + t] = s_ids[p + t];
        if (t >= 4 && t < 4 + p) out_ids[S + 2560 - p + (t - 4)] = s_ids[2560 + (t - 4)];
    }

    // ---- codes x2: naturally 16B-aligned ----
    const size_t baseC = ((size_t)b * NF_ + j0) * 9;
    const vf4* sc4 = (const vf4*)s_codes;
    vf4* c1p = (vf4*)(out + OFF_C1 + baseC);
    vf4* c2p = (vf4*)(out + OFF_C2 + baseC);
    for (int f4 = t; f4 < 576; f4 += 256) {
        vf4 v = sc4[f4];
        c1p[f4] = v;
        c2p[f4] = v;
    }

    // ---- final ids pad + recon_faces ----
    if (t == 0) {
        if (j0 == NF_ - 256)
            out_ids[(size_t)b * ROW_ + (ROW_ - 1)] = -1.0f;
        if (j0 == 0) {  // thread 0 of first block holds face 0's codes
            float* out_rec = out + OFF_REC;
            #pragma unroll
            for (int k = 0; k < 9; ++k)
                out_rec[b * 9 + k] = (code_f[k] + 0.5f) * 0.015625f - 1.0f;
        }
    }
}

extern "C" void kernel_launch(void* const* d_in, const int* in_sizes, int n_in,
                              void* d_out, int out_size, void* d_ws, size_t ws_size,
                              hipStream_t stream) {
    const float*  verts  = (const float*)d_in[0];
    const int*    faces  = (const int*)d_in[1];
    float*        out    = (float*)d_out;
    unsigned int* packed = (unsigned int*)d_ws;   // 2 MB: 64*8192 uints

    pack_verts_kernel<<<dim3(B_ * NV_ / 256), dim3(256), 0, stream>>>(verts, packed);
    mesh_tok_kernel  <<<dim3(B_ * (NF_ / 256)), dim3(256), 0, stream>>>(packed, faces, out);
}